// Round 18
// baseline (108.129 us; speedup 1.0000x reference)
//
#include <hip/hip_runtime.h>
#include <hip/hip_bf16.h>

#define DIM_D 1024
#define DIM_KH 64
#define SEQ   2048
#define BATCH 8
#define NROWS (BATCH*SEQ)   // 16384
#define KVSPLIT 8
#define KEYS_PER_SPLIT (SEQ/KVSPLIT)   // 256

typedef __attribute__((ext_vector_type(8))) short short8;
typedef __attribute__((ext_vector_type(4))) short short4v;
typedef __attribute__((ext_vector_type(4))) float floatx4;

__device__ __forceinline__ ushort f2bf(float f) {
    union { __hip_bfloat16 h; ushort u; } cv;
    cv.h = __float2bfloat16(f);
    return cv.u;
}

__device__ __forceinline__ float bf2f(ushort u) {
    union { float f; uint u32; } c;
    c.u32 = (uint)u << 16;
    return c.f;
}

__device__ __forceinline__ uint4 pack8(float4 a, float4 b) {
    uint4 p;
    p.x = (uint)f2bf(a.x) | ((uint)f2bf(a.y) << 16);
    p.y = (uint)f2bf(a.z) | ((uint)f2bf(a.w) << 16);
    p.z = (uint)f2bf(b.x) | ((uint)f2bf(b.y) << 16);
    p.w = (uint)f2bf(b.z) | ((uint)f2bf(b.w) << 16);
    return p;
}

// ---------------------------------------------------------------------------
// Kernel 0: all weight converts in ONE launch.
// ---------------------------------------------------------------------------
__global__ void wconv_all(const float* __restrict__ Wq,
                          const float* __restrict__ Wk,
                          const float* __restrict__ Wv,
                          const float* __restrict__ Wo,
                          ushort* __restrict__ WT,
                          ushort* __restrict__ WoT)
{
    const int tid = threadIdx.x;
    if (blockIdx.x < 192) {
        const int n  = blockIdx.x;
        const int o  = n >> 6;
        const int nn = n & 63;
        const float* W = (o == 0) ? Wq : (o == 1) ? Wk : Wv;
        #pragma unroll
        for (int i = 0; i < 4; i++) {
            int k = tid + i * 256;
            WT[(size_t)n * DIM_D + k] = f2bf(W[(size_t)k * DIM_KH + nn]);
        }
    } else {
        const int blk = blockIdx.x - 192;
        const int n = blk * 4 + (tid >> 6);   // 0..1023
        const int k = tid & 63;
        WoT[(size_t)n * DIM_KH + k] = f2bf(Wo[(size_t)k * DIM_D + n]);
    }
}

// ---------------------------------------------------------------------------
// Kernel 1: QKV projection, bf16 MFMA, reg prefetch + double-buffered LDS.
// (unchanged — proven R8)
// ---------------------------------------------------------------------------
__global__ __launch_bounds__(256, 1) void qkv_mfma(
    const float* __restrict__ X, const ushort* __restrict__ WT,
    const float* __restrict__ bq, const float* __restrict__ bk,
    const float* __restrict__ bv,
    ushort* __restrict__ Qb, ushort* __restrict__ Kb, ushort* __restrict__ Vb)
{
    const int tid = threadIdx.x;
    const int m0  = blockIdx.x * 64;
    const int o   = blockIdx.y;          // 0=Q 1=K 2=V

    __shared__ ushort Xs[2][64 * 64];
    __shared__ ushort Wls[2][64 * 64];

    const int w  = tid >> 6;
    const int l  = tid & 63;
    const int ql = l & 15;
    const int g  = (l >> 4) & 3;
    const int swz = (ql & 7) << 3;

    const int sr  = tid >> 2;
    const int sc  = (tid & 3) << 4;
    const int ssw = (sr & 7) << 3;
    const float*  Xrow = X  + (size_t)(m0 + sr) * DIM_D + sc;
    const ushort* Wrow = WT + (size_t)(o * 64 + sr) * DIM_D + sc;

    float4 xr[4];
    uint4  wr[2];

    floatx4 acc[4];
    #pragma unroll
    for (int fn = 0; fn < 4; fn++) acc[fn] = (floatx4){0.f, 0.f, 0.f, 0.f};

    #pragma unroll
    for (int f = 0; f < 4; f++)
        xr[f] = *reinterpret_cast<const float4*>(Xrow + f * 4);
    #pragma unroll
    for (int h = 0; h < 2; h++)
        wr[h] = *reinterpret_cast<const uint4*>(Wrow + h * 8);
    #pragma unroll
    for (int h = 0; h < 2; h++) {
        *reinterpret_cast<uint4*>(&Xs[0][sr * 64 + ((sc + h * 8) ^ ssw)]) =
            pack8(xr[2 * h], xr[2 * h + 1]);
        *reinterpret_cast<uint4*>(&Wls[0][sr * 64 + ((sc + h * 8) ^ ssw)]) = wr[h];
    }
    __syncthreads();

    #pragma unroll
    for (int t = 0; t < 16; t++) {
        const int cur = t & 1;
        const int nxt = cur ^ 1;
        if (t < 15) {
            const int k1 = (t + 1) * 64;
            #pragma unroll
            for (int f = 0; f < 4; f++)
                xr[f] = *reinterpret_cast<const float4*>(Xrow + k1 + f * 4);
            #pragma unroll
            for (int h = 0; h < 2; h++)
                wr[h] = *reinterpret_cast<const uint4*>(Wrow + k1 + h * 8);
        }

        #pragma unroll
        for (int kk = 0; kk < 2; kk++) {
            short8 a = *reinterpret_cast<const short8*>(
                &Xs[cur][(16 * w + ql) * 64 + ((kk * 32 + g * 8) ^ swz)]);
            #pragma unroll
            for (int fn = 0; fn < 4; fn++) {
                short8 b = *reinterpret_cast<const short8*>(
                    &Wls[cur][(16 * fn + ql) * 64 + ((kk * 32 + g * 8) ^ swz)]);
                acc[fn] = __builtin_amdgcn_mfma_f32_16x16x32_bf16(a, b, acc[fn], 0, 0, 0);
            }
        }

        if (t < 15) {
            #pragma unroll
            for (int h = 0; h < 2; h++) {
                *reinterpret_cast<uint4*>(&Xs[nxt][sr * 64 + ((sc + h * 8) ^ ssw)]) =
                    pack8(xr[2 * h], xr[2 * h + 1]);
                *reinterpret_cast<uint4*>(&Wls[nxt][sr * 64 + ((sc + h * 8) ^ ssw)]) = wr[h];
            }
        }
        __syncthreads();
    }

    const float* bias = (o == 0) ? bq : (o == 1) ? bk : bv;
    ushort* O = (o == 0) ? Qb : (o == 1) ? Kb : Vb;
    float bvreg[4];
    #pragma unroll
    for (int fn = 0; fn < 4; fn++) bvreg[fn] = bias[16 * fn + ql];

    #pragma unroll
    for (int fn = 0; fn < 4; fn++) {
        #pragma unroll
        for (int r = 0; r < 4; r++) {
            int row = m0 + 16 * w + 4 * g + r;
            O[(size_t)row * DIM_KH + 16 * fn + ql] = f2bf(acc[fn][r] + bvreg[fn]);
        }
    }
}

// ---------------------------------------------------------------------------
// Kernel 2: flash attention, bf16 MFMA, split-KV (now 8 splits -> 2048 blocks
// = 8 blocks/CU, doubling latency overlap). Core unchanged.
// ---------------------------------------------------------------------------
__global__ __launch_bounds__(256) void attn_mfma(
    const ushort* __restrict__ Qb, const ushort* __restrict__ Kb,
    const ushort* __restrict__ Vb,
    ushort* __restrict__ OpartB, float* __restrict__ Ml)
{
    const int tid = threadIdx.x;
    const int w   = tid >> 6;
    const int l   = tid & 63;
    const int ql  = l & 15;
    const int g   = (l >> 4) & 3;
    const int q0  = blockIdx.x * 64;
    const int s   = blockIdx.y;          // KV split
    const int b   = blockIdx.z;
    const int swzq = (ql & 7) << 3;

    __shared__ ushort Ks[64 * 64];   // [key][dim], swizzled by key (row&7)<<3
    __shared__ ushort VTs[64 * 64];  // [dim][key], swizzled by (dim&15)<<2

    short8 qf[2];
    #pragma unroll
    for (int kk = 0; kk < 2; kk++) {
        qf[kk] = *reinterpret_cast<const short8*>(
            Qb + ((size_t)(b * SEQ + q0 + 16 * w + ql)) * DIM_KH + kk * 32 + g * 8);
    }

    floatx4 accv[4];
    #pragma unroll
    for (int fd = 0; fd < 4; fd++) accv[fd] = (floatx4){0.f, 0.f, 0.f, 0.f};
    float m_run = -3.0e38f, l_run = 0.f;

    const ushort* Kbb = Kb + (size_t)b * SEQ * DIM_KH;
    const ushort* Vbb = Vb + (size_t)b * SEQ * DIM_KH;
    const int t_begin = s * KEYS_PER_SPLIT;
    const int t_end   = t_begin + KEYS_PER_SPLIT;

    for (int t0 = t_begin; t0 < t_end; t0 += 64) {
        __syncthreads();
        #pragma unroll
        for (int i = 0; i < 2; i++) {
            int idx = tid + i * 256;
            int row = idx >> 3;
            int ch  = idx & 7;
            uint4 v = *reinterpret_cast<const uint4*>(
                Kbb + (size_t)(t0 + row) * DIM_KH + ch * 8);
            *reinterpret_cast<uint4*>(&Ks[row * 64 + ((ch * 8) ^ ((row & 7) << 3))]) = v;
        }
        {
            int kg = tid >> 4, dg = tid & 15;
            int key0 = kg * 4, dim0 = dg * 4;
            uint2 vr[4];
            #pragma unroll
            for (int i = 0; i < 4; i++)
                vr[i] = *reinterpret_cast<const uint2*>(
                    Vbb + (size_t)(t0 + key0 + i) * DIM_KH + dim0);
            #pragma unroll
            for (int j = 0; j < 4; j++) {
                uint e0 = (j == 0) ? (vr[0].x & 0xffffu) : (j == 1) ? (vr[0].x >> 16)
                        : (j == 2) ? (vr[0].y & 0xffffu) : (vr[0].y >> 16);
                uint e1 = (j == 0) ? (vr[1].x & 0xffffu) : (j == 1) ? (vr[1].x >> 16)
                        : (j == 2) ? (vr[1].y & 0xffffu) : (vr[1].y >> 16);
                uint e2 = (j == 0) ? (vr[2].x & 0xffffu) : (j == 1) ? (vr[2].x >> 16)
                        : (j == 2) ? (vr[2].y & 0xffffu) : (vr[2].y >> 16);
                uint e3 = (j == 0) ? (vr[3].x & 0xffffu) : (j == 1) ? (vr[3].x >> 16)
                        : (j == 2) ? (vr[3].y & 0xffffu) : (vr[3].y >> 16);
                uint2 p; p.x = e0 | (e1 << 16); p.y = e2 | (e3 << 16);
                int dim = dim0 + j;
                int addr = dim * 64 + (key0 ^ ((dim & 15) << 2));
                *reinterpret_cast<uint2*>(&VTs[addr]) = p;
            }
        }
        __syncthreads();

        floatx4 sfrag[4];
        #pragma unroll
        for (int f = 0; f < 4; f++) {
            sfrag[f] = (floatx4){0.f, 0.f, 0.f, 0.f};
            #pragma unroll
            for (int kk = 0; kk < 2; kk++) {
                short8 a = *reinterpret_cast<const short8*>(
                    &Ks[(16 * f + ql) * 64 + ((kk * 32 + g * 8) ^ swzq)]);
                sfrag[f] = __builtin_amdgcn_mfma_f32_16x16x32_bf16(a, qf[kk], sfrag[f], 0, 0, 0);
            }
        }

        float mt = -3.0e38f;
        #pragma unroll
        for (int f = 0; f < 4; f++)
            #pragma unroll
            for (int r = 0; r < 4; r++) mt = fmaxf(mt, sfrag[f][r]);
        mt = fmaxf(mt, __shfl_xor(mt, 16));
        mt = fmaxf(mt, __shfl_xor(mt, 32));
        float m_new = fmaxf(m_run, mt);
        float sc = __expf((m_run - m_new) * 0.125f);
        float psum = 0.f;
        ushort pb[4][4];
        #pragma unroll
        for (int f = 0; f < 4; f++)
            #pragma unroll
            for (int r = 0; r < 4; r++) {
                float p = __expf((sfrag[f][r] - m_new) * 0.125f);
                pb[f][r] = f2bf(p);
                psum += p;
            }
        psum += __shfl_xor(psum, 16);
        psum += __shfl_xor(psum, 32);
        l_run = l_run * sc + psum;
        m_run = m_new;

        float s0 = __shfl(sc, 4 * g + 0);
        float s1 = __shfl(sc, 4 * g + 1);
        float s2 = __shfl(sc, 4 * g + 2);
        float s3 = __shfl(sc, 4 * g + 3);
        #pragma unroll
        for (int fd = 0; fd < 4; fd++) {
            accv[fd][0] *= s0; accv[fd][1] *= s1;
            accv[fd][2] *= s2; accv[fd][3] *= s3;
        }

        short8 pa_lo, pa_hi;
        pa_lo[0] = (short)pb[0][0]; pa_lo[1] = (short)pb[0][1];
        pa_lo[2] = (short)pb[0][2]; pa_lo[3] = (short)pb[0][3];
        pa_lo[4] = (short)pb[1][0]; pa_lo[5] = (short)pb[1][1];
        pa_lo[6] = (short)pb[1][2]; pa_lo[7] = (short)pb[1][3];
        pa_hi[0] = (short)pb[2][0]; pa_hi[1] = (short)pb[2][1];
        pa_hi[2] = (short)pb[2][2]; pa_hi[3] = (short)pb[2][3];
        pa_hi[4] = (short)pb[3][0]; pa_hi[5] = (short)pb[3][1];
        pa_hi[6] = (short)pb[3][2]; pa_hi[7] = (short)pb[3][3];

        #pragma unroll
        for (int fd = 0; fd < 4; fd++) {
            int dim = 16 * fd + ql;
            int base = dim * 64;
            int sw = (dim & 15) << 2;
            short4v v0 = *reinterpret_cast<const short4v*>(&VTs[base + ((4 * g) ^ sw)]);
            short4v v1 = *reinterpret_cast<const short4v*>(&VTs[base + ((16 + 4 * g) ^ sw)]);
            short8 bb;
            bb[0] = v0[0]; bb[1] = v0[1]; bb[2] = v0[2]; bb[3] = v0[3];
            bb[4] = v1[0]; bb[5] = v1[1]; bb[6] = v1[2]; bb[7] = v1[3];
            accv[fd] = __builtin_amdgcn_mfma_f32_16x16x32_bf16(pa_lo, bb, accv[fd], 0, 0, 0);
            short4v v2 = *reinterpret_cast<const short4v*>(&VTs[base + ((32 + 4 * g) ^ sw)]);
            short4v v3 = *reinterpret_cast<const short4v*>(&VTs[base + ((48 + 4 * g) ^ sw)]);
            short8 bb2;
            bb2[0] = v2[0]; bb2[1] = v2[1]; bb2[2] = v2[2]; bb2[3] = v2[3];
            bb2[4] = v3[0]; bb2[5] = v3[1]; bb2[6] = v3[2]; bb2[7] = v3[3];
            accv[fd] = __builtin_amdgcn_mfma_f32_16x16x32_bf16(pa_hi, bb2, accv[fd], 0, 0, 0);
        }
    }

    const size_t rid0 = (size_t)b * SEQ + q0;
    if (g == 0) {
        size_t rid = rid0 + 16 * w + ql;
        Ml[((size_t)s * NROWS + rid) * 2 + 0] = m_run;
        Ml[((size_t)s * NROWS + rid) * 2 + 1] = l_run;
    }
    #pragma unroll
    for (int fd = 0; fd < 4; fd++) {
        int col = 16 * fd + ql;
        size_t rbase = (size_t)s * NROWS + rid0 + 16 * w + 4 * g;
        OpartB[(rbase + 0) * DIM_KH + col] = f2bf(accv[fd][0]);
        OpartB[(rbase + 1) * DIM_KH + col] = f2bf(accv[fd][1]);
        OpartB[(rbase + 2) * DIM_KH + col] = f2bf(accv[fd][2]);
        OpartB[(rbase + 3) * DIM_KH + col] = f2bf(accv[fd][3]);
    }
}

// ---------------------------------------------------------------------------
// Kernel 3: fused combine + out-proj + residual + LayerNorm. (R17 structure;
// combine loop now over 8 splits.)
// ---------------------------------------------------------------------------
__global__ __launch_bounds__(512, 1) void out_mfma(
    const float* __restrict__ X, const ushort* __restrict__ OpartB,
    const float* __restrict__ Ml,
    const ushort* __restrict__ WoT, const float* __restrict__ bo,
    const float* __restrict__ gamma, const float* __restrict__ beta,
    float* __restrict__ Out)
{
    const int tid = threadIdx.x;
    const int w   = tid >> 6;            // 0..7
    const int l   = tid & 63;
    const int ql  = l & 15;
    const int g   = (l >> 4) & 3;
    const int row0 = blockIdx.x * 16;
    const int c0  = w * 128;             // 128 cols per wave

    __shared__ ushort Ls[16 * 1024];     // 32 KB bf16

    // ---- T14: issue coalesced-phase X loads NOW (non-temporal, read-once)
    const int r  = tid >> 5;             // 0..15 (32 threads per row)
    const int cb = (tid & 31) * 4;       // 0..124
    const float* Xrow = X + (size_t)(row0 + r) * DIM_D;
    floatx4 xv[8];
    #pragma unroll
    for (int j = 0; j < 8; j++)
        xv[j] = __builtin_nontemporal_load(
            reinterpret_cast<const floatx4*>(Xrow + cb + 128 * j));

    // ---- inline split-combine: build this lane's AV B-frags (row = row0+ql)
    const size_t rid = (size_t)row0 + ql;
    float m[KVSPLIT], lv[KVSPLIT];
    float M = -3.0e38f;
    #pragma unroll
    for (int s = 0; s < KVSPLIT; s++) {
        float2 t = *reinterpret_cast<const float2*>(Ml + ((size_t)s * NROWS + rid) * 2);
        m[s] = t.x; lv[s] = t.y;
        M = fmaxf(M, m[s]);
    }
    float wsum = 0.f;
    float o[16];
    #pragma unroll
    for (int d = 0; d < 16; d++) o[d] = 0.f;
    #pragma unroll
    for (int s = 0; s < KVSPLIT; s++) {
        float wgt = __expf((m[s] - M) * 0.125f);
        wsum = fmaf(wgt, lv[s], wsum);
        const ushort* op = OpartB + ((size_t)s * NROWS + rid) * DIM_KH;
        union { uint4 u; ushort us[8]; } a, b;
        a.u = *reinterpret_cast<const uint4*>(op + g * 8);
        b.u = *reinterpret_cast<const uint4*>(op + 32 + g * 8);
        #pragma unroll
        for (int j = 0; j < 8; j++) {
            o[j]     = fmaf(wgt, bf2f(a.us[j]), o[j]);
            o[8 + j] = fmaf(wgt, bf2f(b.us[j]), o[8 + j]);
        }
    }
    float avinv = 1.0f / wsum;
    short8 bf0, bf1;
    #pragma unroll
    for (int j = 0; j < 8; j++) {
        bf0[j] = (short)f2bf(o[j] * avinv);
        bf1[j] = (short)f2bf(o[8 + j] * avinv);
    }

    // ---- GEMM phase with 2-deep WoT register pipeline (8 ft per wave)
    const ushort* apb = WoT + (size_t)(c0 + ql) * DIM_KH + g * 8;
    short8 a0c = *reinterpret_cast<const short8*>(apb);
    short8 a1c = *reinterpret_cast<const short8*>(apb + 32);
    #pragma unroll
    for (int ft = 0; ft < 8; ft++) {
        short8 a0n, a1n;
        if (ft < 7) {
            const ushort* apn = apb + (size_t)(ft + 1) * 16 * DIM_KH;
            a0n = *reinterpret_cast<const short8*>(apn);
            a1n = *reinterpret_cast<const short8*>(apn + 32);
        }
        floatx4 z = (floatx4){0.f, 0.f, 0.f, 0.f};
        z = __builtin_amdgcn_mfma_f32_16x16x32_bf16(a0c, bf0, z, 0, 0, 0);
        z = __builtin_amdgcn_mfma_f32_16x16x32_bf16(a1c, bf1, z, 0, 0, 0);
        int col = (c0 + 16 * ft + 4 * g) ^ ((ql & 7) << 2);
        uint2 p;
        p.x = (uint)f2bf(z[0]) | ((uint)f2bf(z[1]) << 16);
        p.y = (uint)f2bf(z[2]) | ((uint)f2bf(z[3]) << 16);
        *reinterpret_cast<uint2*>(&Ls[ql * 1024 + col]) = p;
        if (ft < 7) { a0c = a0n; a1c = a1n; }
    }

    // Pin the X prefetch before the barrier.
    #pragma unroll
    for (int j = 0; j < 8; j++)
        asm volatile("" :: "v"(xv[j][0]), "v"(xv[j][1]), "v"(xv[j][2]), "v"(xv[j][3]));
    __syncthreads();

    // ---- pass 1: y = Ls + X + bo; write y back in-place (bf16); acc stats
    const int rsw = (r & 7) << 2;
    float s = 0.f, sq = 0.f;
    #pragma unroll
    for (int j = 0; j < 8; j++) {
        int col = cb + 128 * j;
        ushort* slot = &Ls[r * 1024 + (col ^ rsw)];
        union { uint2 u; ushort us[4]; } a;
        a.u = *reinterpret_cast<const uint2*>(slot);
        float4 b4 = *reinterpret_cast<const float4*>(bo + col);
        ushort y0u = f2bf(bf2f(a.us[0]) + xv[j][0] + b4.x);
        ushort y1u = f2bf(bf2f(a.us[1]) + xv[j][1] + b4.y);
        ushort y2u = f2bf(bf2f(a.us[2]) + xv[j][2] + b4.z);
        ushort y3u = f2bf(bf2f(a.us[3]) + xv[j][3] + b4.w);
        float y0 = bf2f(y0u), y1 = bf2f(y1u), y2 = bf2f(y2u), y3 = bf2f(y3u);
        s  += (y0 + y1) + (y2 + y3);
        sq += fmaf(y0, y0, fmaf(y1, y1, fmaf(y2, y2, y3 * y3)));
        uint2 p;
        p.x = (uint)y0u | ((uint)y1u << 16);
        p.y = (uint)y2u | ((uint)y3u << 16);
        *reinterpret_cast<uint2*>(slot) = p;
    }
    s  += __shfl_xor(s, 1);  s  += __shfl_xor(s, 2);  s  += __shfl_xor(s, 4);
    s  += __shfl_xor(s, 8);  s  += __shfl_xor(s, 16);
    sq += __shfl_xor(sq, 1); sq += __shfl_xor(sq, 2); sq += __shfl_xor(sq, 4);
    sq += __shfl_xor(sq, 8); sq += __shfl_xor(sq, 16);

    float mu  = s * (1.0f / 1024.0f);
    float var = fmaf(sq, (1.0f / 1024.0f), -mu * mu);
    float inv = rsqrtf(var + 1e-5f);

    // ---- pass 2: re-read own slots, normalize, store
    float* Orow = Out + (size_t)(row0 + r) * DIM_D;
    #pragma unroll
    for (int j = 0; j < 8; j++) {
        int col = cb + 128 * j;
        union { uint2 u; ushort us[4]; } a;
        a.u = *reinterpret_cast<const uint2*>(&Ls[r * 1024 + (col ^ rsw)]);
        float4 g4  = *reinterpret_cast<const float4*>(gamma + col);
        float4 be4 = *reinterpret_cast<const float4*>(beta + col);
        floatx4 ov;
        ov[0] = fmaf((bf2f(a.us[0]) - mu) * inv, g4.x, be4.x);
        ov[1] = fmaf((bf2f(a.us[1]) - mu) * inv, g4.y, be4.y);
        ov[2] = fmaf((bf2f(a.us[2]) - mu) * inv, g4.z, be4.z);
        ov[3] = fmaf((bf2f(a.us[3]) - mu) * inv, g4.w, be4.w);
        __builtin_nontemporal_store(ov, reinterpret_cast<floatx4*>(Orow + col));
    }
}

// ---------------------------------------------------------------------------
extern "C" void kernel_launch(void* const* d_in, const int* in_sizes, int n_in,
                              void* d_out, int out_size, void* d_ws, size_t ws_size,
                              hipStream_t stream)
{
    (void)in_sizes; (void)n_in; (void)out_size; (void)ws_size;
    const float* X     = (const float*)d_in[0];
    const float* Wq    = (const float*)d_in[1];
    const float* bq    = (const float*)d_in[2];
    const float* Wk    = (const float*)d_in[3];
    const float* bk    = (const float*)d_in[4];
    const float* Wv    = (const float*)d_in[5];
    const float* bv    = (const float*)d_in[6];
    const float* Wo    = (const float*)d_in[7];
    const float* bo    = (const float*)d_in[8];
    const float* gamma = (const float*)d_in[9];
    const float* beta  = (const float*)d_in[10];
    float* Out = (float*)d_out;

    ushort* Qb  = (ushort*)d_ws;                          // 2 MB bf16
    ushort* Kb  = Qb + (size_t)NROWS * DIM_KH;            // 2 MB
    ushort* Vb  = Kb + (size_t)NROWS * DIM_KH;            // 2 MB
    ushort* WT  = Vb + (size_t)NROWS * DIM_KH;            // 384 KB
    ushort* WoT = WT + (size_t)192 * DIM_D;               // 128 KB
    ushort* OpartB = WoT + (size_t)DIM_D * DIM_KH;        // 16 MB bf16 (8 splits)
    float*  Ml  = (float*)(OpartB + (size_t)KVSPLIT * NROWS * DIM_KH);  // 1 MB

    wconv_all<<<448, 256, 0, stream>>>(Wq, Wk, Wv, Wo, WT, WoT);
    qkv_mfma<<<dim3(256, 3), 256, 0, stream>>>(X, WT, bq, bk, bv, Qb, Kb, Vb);
    attn_mfma<<<dim3(SEQ/64, KVSPLIT, BATCH), 256, 0, stream>>>(Qb, Kb, Vb, OpartB, Ml);
    out_mfma<<<NROWS/16, 512, 0, stream>>>(X, OpartB, Ml, WoT, bo, gamma, beta, Out);
}

// Round 19
// 94.616 us; speedup vs baseline: 1.1428x; 1.1428x over previous
//
#include <hip/hip_runtime.h>
#include <hip/hip_bf16.h>

#define DIM_D 1024
#define DIM_KH 64
#define SEQ   2048
#define BATCH 8
#define NROWS (BATCH*SEQ)   // 16384
#define KVSPLIT 4
#define KEYS_PER_SPLIT (SEQ/KVSPLIT)   // 512

typedef __attribute__((ext_vector_type(8))) short short8;
typedef __attribute__((ext_vector_type(4))) short short4v;
typedef __attribute__((ext_vector_type(4))) float floatx4;

__device__ __forceinline__ ushort f2bf(float f) {
    union { __hip_bfloat16 h; ushort u; } cv;
    cv.h = __float2bfloat16(f);
    return cv.u;
}

__device__ __forceinline__ float bf2f(ushort u) {
    union { float f; uint u32; } c;
    c.u32 = (uint)u << 16;
    return c.f;
}

__device__ __forceinline__ uint4 pack8(float4 a, float4 b) {
    uint4 p;
    p.x = (uint)f2bf(a.x) | ((uint)f2bf(a.y) << 16);
    p.y = (uint)f2bf(a.z) | ((uint)f2bf(a.w) << 16);
    p.z = (uint)f2bf(b.x) | ((uint)f2bf(b.y) << 16);
    p.w = (uint)f2bf(b.z) | ((uint)f2bf(b.w) << 16);
    return p;
}

// ---------------------------------------------------------------------------
// Kernel 0: all weight converts in ONE launch.
// ---------------------------------------------------------------------------
__global__ void wconv_all(const float* __restrict__ Wq,
                          const float* __restrict__ Wk,
                          const float* __restrict__ Wv,
                          const float* __restrict__ Wo,
                          ushort* __restrict__ WT,
                          ushort* __restrict__ WoT)
{
    const int tid = threadIdx.x;
    if (blockIdx.x < 192) {
        const int n  = blockIdx.x;
        const int o  = n >> 6;
        const int nn = n & 63;
        const float* W = (o == 0) ? Wq : (o == 1) ? Wk : Wv;
        #pragma unroll
        for (int i = 0; i < 4; i++) {
            int k = tid + i * 256;
            WT[(size_t)n * DIM_D + k] = f2bf(W[(size_t)k * DIM_KH + nn]);
        }
    } else {
        const int blk = blockIdx.x - 192;
        const int n = blk * 4 + (tid >> 6);   // 0..1023
        const int k = tid & 63;
        WoT[(size_t)n * DIM_KH + k] = f2bf(Wo[(size_t)k * DIM_D + n]);
    }
}

// ---------------------------------------------------------------------------
// Kernel 1: QKV projection, bf16 MFMA, reg prefetch + double-buffered LDS.
// (unchanged — proven R8)
// ---------------------------------------------------------------------------
__global__ __launch_bounds__(256, 1) void qkv_mfma(
    const float* __restrict__ X, const ushort* __restrict__ WT,
    const float* __restrict__ bq, const float* __restrict__ bk,
    const float* __restrict__ bv,
    ushort* __restrict__ Qb, ushort* __restrict__ Kb, ushort* __restrict__ Vb)
{
    const int tid = threadIdx.x;
    const int m0  = blockIdx.x * 64;
    const int o   = blockIdx.y;          // 0=Q 1=K 2=V

    __shared__ ushort Xs[2][64 * 64];
    __shared__ ushort Wls[2][64 * 64];

    const int w  = tid >> 6;
    const int l  = tid & 63;
    const int ql = l & 15;
    const int g  = (l >> 4) & 3;
    const int swz = (ql & 7) << 3;

    const int sr  = tid >> 2;
    const int sc  = (tid & 3) << 4;
    const int ssw = (sr & 7) << 3;
    const float*  Xrow = X  + (size_t)(m0 + sr) * DIM_D + sc;
    const ushort* Wrow = WT + (size_t)(o * 64 + sr) * DIM_D + sc;

    float4 xr[4];
    uint4  wr[2];

    floatx4 acc[4];
    #pragma unroll
    for (int fn = 0; fn < 4; fn++) acc[fn] = (floatx4){0.f, 0.f, 0.f, 0.f};

    #pragma unroll
    for (int f = 0; f < 4; f++)
        xr[f] = *reinterpret_cast<const float4*>(Xrow + f * 4);
    #pragma unroll
    for (int h = 0; h < 2; h++)
        wr[h] = *reinterpret_cast<const uint4*>(Wrow + h * 8);
    #pragma unroll
    for (int h = 0; h < 2; h++) {
        *reinterpret_cast<uint4*>(&Xs[0][sr * 64 + ((sc + h * 8) ^ ssw)]) =
            pack8(xr[2 * h], xr[2 * h + 1]);
        *reinterpret_cast<uint4*>(&Wls[0][sr * 64 + ((sc + h * 8) ^ ssw)]) = wr[h];
    }
    __syncthreads();

    #pragma unroll
    for (int t = 0; t < 16; t++) {
        const int cur = t & 1;
        const int nxt = cur ^ 1;
        if (t < 15) {
            const int k1 = (t + 1) * 64;
            #pragma unroll
            for (int f = 0; f < 4; f++)
                xr[f] = *reinterpret_cast<const float4*>(Xrow + k1 + f * 4);
            #pragma unroll
            for (int h = 0; h < 2; h++)
                wr[h] = *reinterpret_cast<const uint4*>(Wrow + k1 + h * 8);
        }

        #pragma unroll
        for (int kk = 0; kk < 2; kk++) {
            short8 a = *reinterpret_cast<const short8*>(
                &Xs[cur][(16 * w + ql) * 64 + ((kk * 32 + g * 8) ^ swz)]);
            #pragma unroll
            for (int fn = 0; fn < 4; fn++) {
                short8 b = *reinterpret_cast<const short8*>(
                    &Wls[cur][(16 * fn + ql) * 64 + ((kk * 32 + g * 8) ^ swz)]);
                acc[fn] = __builtin_amdgcn_mfma_f32_16x16x32_bf16(a, b, acc[fn], 0, 0, 0);
            }
        }

        if (t < 15) {
            #pragma unroll
            for (int h = 0; h < 2; h++) {
                *reinterpret_cast<uint4*>(&Xs[nxt][sr * 64 + ((sc + h * 8) ^ ssw)]) =
                    pack8(xr[2 * h], xr[2 * h + 1]);
                *reinterpret_cast<uint4*>(&Wls[nxt][sr * 64 + ((sc + h * 8) ^ ssw)]) = wr[h];
            }
        }
        __syncthreads();
    }

    const float* bias = (o == 0) ? bq : (o == 1) ? bk : bv;
    ushort* O = (o == 0) ? Qb : (o == 1) ? Kb : Vb;
    float bvreg[4];
    #pragma unroll
    for (int fn = 0; fn < 4; fn++) bvreg[fn] = bias[16 * fn + ql];

    #pragma unroll
    for (int fn = 0; fn < 4; fn++) {
        #pragma unroll
        for (int r = 0; r < 4; r++) {
            int row = m0 + 16 * w + 4 * g + r;
            O[(size_t)row * DIM_KH + 16 * fn + ql] = f2bf(acc[fn][r] + bvreg[fn]);
        }
    }
}

// ---------------------------------------------------------------------------
// Kernel 2: flash attention, bf16 MFMA, split-KV, bf16 partials. (unchanged)
// ---------------------------------------------------------------------------
__global__ __launch_bounds__(256) void attn_mfma(
    const ushort* __restrict__ Qb, const ushort* __restrict__ Kb,
    const ushort* __restrict__ Vb,
    ushort* __restrict__ OpartB, float* __restrict__ Ml)
{
    const int tid = threadIdx.x;
    const int w   = tid >> 6;
    const int l   = tid & 63;
    const int ql  = l & 15;
    const int g   = (l >> 4) & 3;
    const int q0  = blockIdx.x * 64;
    const int s   = blockIdx.y;          // KV split
    const int b   = blockIdx.z;
    const int swzq = (ql & 7) << 3;

    __shared__ ushort Ks[64 * 64];   // [key][dim], swizzled by key (row&7)<<3
    __shared__ ushort VTs[64 * 64];  // [dim][key], swizzled by (dim&15)<<2

    short8 qf[2];
    #pragma unroll
    for (int kk = 0; kk < 2; kk++) {
        qf[kk] = *reinterpret_cast<const short8*>(
            Qb + ((size_t)(b * SEQ + q0 + 16 * w + ql)) * DIM_KH + kk * 32 + g * 8);
    }

    floatx4 accv[4];
    #pragma unroll
    for (int fd = 0; fd < 4; fd++) accv[fd] = (floatx4){0.f, 0.f, 0.f, 0.f};
    float m_run = -3.0e38f, l_run = 0.f;

    const ushort* Kbb = Kb + (size_t)b * SEQ * DIM_KH;
    const ushort* Vbb = Vb + (size_t)b * SEQ * DIM_KH;
    const int t_begin = s * KEYS_PER_SPLIT;
    const int t_end   = t_begin + KEYS_PER_SPLIT;

    for (int t0 = t_begin; t0 < t_end; t0 += 64) {
        __syncthreads();
        #pragma unroll
        for (int i = 0; i < 2; i++) {
            int idx = tid + i * 256;
            int row = idx >> 3;
            int ch  = idx & 7;
            uint4 v = *reinterpret_cast<const uint4*>(
                Kbb + (size_t)(t0 + row) * DIM_KH + ch * 8);
            *reinterpret_cast<uint4*>(&Ks[row * 64 + ((ch * 8) ^ ((row & 7) << 3))]) = v;
        }
        {
            int kg = tid >> 4, dg = tid & 15;
            int key0 = kg * 4, dim0 = dg * 4;
            uint2 vr[4];
            #pragma unroll
            for (int i = 0; i < 4; i++)
                vr[i] = *reinterpret_cast<const uint2*>(
                    Vbb + (size_t)(t0 + key0 + i) * DIM_KH + dim0);
            #pragma unroll
            for (int j = 0; j < 4; j++) {
                uint e0 = (j == 0) ? (vr[0].x & 0xffffu) : (j == 1) ? (vr[0].x >> 16)
                        : (j == 2) ? (vr[0].y & 0xffffu) : (vr[0].y >> 16);
                uint e1 = (j == 0) ? (vr[1].x & 0xffffu) : (j == 1) ? (vr[1].x >> 16)
                        : (j == 2) ? (vr[1].y & 0xffffu) : (vr[1].y >> 16);
                uint e2 = (j == 0) ? (vr[2].x & 0xffffu) : (j == 1) ? (vr[2].x >> 16)
                        : (j == 2) ? (vr[2].y & 0xffffu) : (vr[2].y >> 16);
                uint e3 = (j == 0) ? (vr[3].x & 0xffffu) : (j == 1) ? (vr[3].x >> 16)
                        : (j == 2) ? (vr[3].y & 0xffffu) : (vr[3].y >> 16);
                uint2 p; p.x = e0 | (e1 << 16); p.y = e2 | (e3 << 16);
                int dim = dim0 + j;
                int addr = dim * 64 + (key0 ^ ((dim & 15) << 2));
                *reinterpret_cast<uint2*>(&VTs[addr]) = p;
            }
        }
        __syncthreads();

        floatx4 sfrag[4];
        #pragma unroll
        for (int f = 0; f < 4; f++) {
            sfrag[f] = (floatx4){0.f, 0.f, 0.f, 0.f};
            #pragma unroll
            for (int kk = 0; kk < 2; kk++) {
                short8 a = *reinterpret_cast<const short8*>(
                    &Ks[(16 * f + ql) * 64 + ((kk * 32 + g * 8) ^ swzq)]);
                sfrag[f] = __builtin_amdgcn_mfma_f32_16x16x32_bf16(a, qf[kk], sfrag[f], 0, 0, 0);
            }
        }

        float mt = -3.0e38f;
        #pragma unroll
        for (int f = 0; f < 4; f++)
            #pragma unroll
            for (int r = 0; r < 4; r++) mt = fmaxf(mt, sfrag[f][r]);
        mt = fmaxf(mt, __shfl_xor(mt, 16));
        mt = fmaxf(mt, __shfl_xor(mt, 32));
        float m_new = fmaxf(m_run, mt);
        float sc = __expf((m_run - m_new) * 0.125f);
        float psum = 0.f;
        ushort pb[4][4];
        #pragma unroll
        for (int f = 0; f < 4; f++)
            #pragma unroll
            for (int r = 0; r < 4; r++) {
                float p = __expf((sfrag[f][r] - m_new) * 0.125f);
                pb[f][r] = f2bf(p);
                psum += p;
            }
        psum += __shfl_xor(psum, 16);
        psum += __shfl_xor(psum, 32);
        l_run = l_run * sc + psum;
        m_run = m_new;

        float s0 = __shfl(sc, 4 * g + 0);
        float s1 = __shfl(sc, 4 * g + 1);
        float s2 = __shfl(sc, 4 * g + 2);
        float s3 = __shfl(sc, 4 * g + 3);
        #pragma unroll
        for (int fd = 0; fd < 4; fd++) {
            accv[fd][0] *= s0; accv[fd][1] *= s1;
            accv[fd][2] *= s2; accv[fd][3] *= s3;
        }

        short8 pa_lo, pa_hi;
        pa_lo[0] = (short)pb[0][0]; pa_lo[1] = (short)pb[0][1];
        pa_lo[2] = (short)pb[0][2]; pa_lo[3] = (short)pb[0][3];
        pa_lo[4] = (short)pb[1][0]; pa_lo[5] = (short)pb[1][1];
        pa_lo[6] = (short)pb[1][2]; pa_lo[7] = (short)pb[1][3];
        pa_hi[0] = (short)pb[2][0]; pa_hi[1] = (short)pb[2][1];
        pa_hi[2] = (short)pb[2][2]; pa_hi[3] = (short)pb[2][3];
        pa_hi[4] = (short)pb[3][0]; pa_hi[5] = (short)pb[3][1];
        pa_hi[6] = (short)pb[3][2]; pa_hi[7] = (short)pb[3][3];

        #pragma unroll
        for (int fd = 0; fd < 4; fd++) {
            int dim = 16 * fd + ql;
            int base = dim * 64;
            int sw = (dim & 15) << 2;
            short4v v0 = *reinterpret_cast<const short4v*>(&VTs[base + ((4 * g) ^ sw)]);
            short4v v1 = *reinterpret_cast<const short4v*>(&VTs[base + ((16 + 4 * g) ^ sw)]);
            short8 bb;
            bb[0] = v0[0]; bb[1] = v0[1]; bb[2] = v0[2]; bb[3] = v0[3];
            bb[4] = v1[0]; bb[5] = v1[1]; bb[6] = v1[2]; bb[7] = v1[3];
            accv[fd] = __builtin_amdgcn_mfma_f32_16x16x32_bf16(pa_lo, bb, accv[fd], 0, 0, 0);
            short4v v2 = *reinterpret_cast<const short4v*>(&VTs[base + ((32 + 4 * g) ^ sw)]);
            short4v v3 = *reinterpret_cast<const short4v*>(&VTs[base + ((48 + 4 * g) ^ sw)]);
            short8 bb2;
            bb2[0] = v2[0]; bb2[1] = v2[1]; bb2[2] = v2[2]; bb2[3] = v2[3];
            bb2[4] = v3[0]; bb2[5] = v3[1]; bb2[6] = v3[2]; bb2[7] = v3[3];
            accv[fd] = __builtin_amdgcn_mfma_f32_16x16x32_bf16(pa_hi, bb2, accv[fd], 0, 0, 0);
        }
    }

    const size_t rid0 = (size_t)b * SEQ + q0;
    if (g == 0) {
        size_t rid = rid0 + 16 * w + ql;
        Ml[((size_t)s * NROWS + rid) * 2 + 0] = m_run;
        Ml[((size_t)s * NROWS + rid) * 2 + 1] = l_run;
    }
    #pragma unroll
    for (int fd = 0; fd < 4; fd++) {
        int col = 16 * fd + ql;
        size_t rbase = (size_t)s * NROWS + rid0 + 16 * w + 4 * g;
        OpartB[(rbase + 0) * DIM_KH + col] = f2bf(accv[fd][0]);
        OpartB[(rbase + 1) * DIM_KH + col] = f2bf(accv[fd][1]);
        OpartB[(rbase + 2) * DIM_KH + col] = f2bf(accv[fd][2]);
        OpartB[(rbase + 3) * DIM_KH + col] = f2bf(accv[fd][3]);
    }
}

// ---------------------------------------------------------------------------
// Kernel 3: fused combine + out-proj + residual + LayerNorm. (R12 exact —
// best measured variant: 256 threads, bf16 Ls, 2-deep WoT pipeline,
// unpinned X prefetch.)
// ---------------------------------------------------------------------------
__global__ __launch_bounds__(256, 1) void out_mfma(
    const float* __restrict__ X, const ushort* __restrict__ OpartB,
    const float* __restrict__ Ml,
    const ushort* __restrict__ WoT, const float* __restrict__ bo,
    const float* __restrict__ gamma, const float* __restrict__ beta,
    float* __restrict__ Out)
{
    const int tid = threadIdx.x;
    const int w   = tid >> 6;
    const int l   = tid & 63;
    const int ql  = l & 15;
    const int g   = (l >> 4) & 3;
    const int row0 = blockIdx.x * 16;
    const int c0  = w * 256;

    __shared__ ushort Ls[16 * 1024];   // 32 KB bf16

    // ---- X loads for the coalesced phase (issued early; compiler may sink)
    const int r  = tid >> 4;
    const int cb = (tid & 15) * 4;
    const float* Xrow = X + (size_t)(row0 + r) * DIM_D;
    float4 xv[16];
    #pragma unroll
    for (int j = 0; j < 16; j++)
        xv[j] = *reinterpret_cast<const float4*>(Xrow + cb + 64 * j);

    // ---- inline split-combine: build this lane's AV B-frags
    const size_t rid = (size_t)row0 + ql;
    float m[KVSPLIT], lv[KVSPLIT];
    float M = -3.0e38f;
    #pragma unroll
    for (int s = 0; s < KVSPLIT; s++) {
        float2 t = *reinterpret_cast<const float2*>(Ml + ((size_t)s * NROWS + rid) * 2);
        m[s] = t.x; lv[s] = t.y;
        M = fmaxf(M, m[s]);
    }
    float wsum = 0.f;
    float o[16];
    #pragma unroll
    for (int d = 0; d < 16; d++) o[d] = 0.f;
    #pragma unroll
    for (int s = 0; s < KVSPLIT; s++) {
        float wgt = __expf((m[s] - M) * 0.125f);
        wsum = fmaf(wgt, lv[s], wsum);
        const ushort* op = OpartB + ((size_t)s * NROWS + rid) * DIM_KH;
        union { uint4 u; ushort us[8]; } a, b;
        a.u = *reinterpret_cast<const uint4*>(op + g * 8);
        b.u = *reinterpret_cast<const uint4*>(op + 32 + g * 8);
        #pragma unroll
        for (int j = 0; j < 8; j++) {
            o[j]     = fmaf(wgt, bf2f(a.us[j]), o[j]);
            o[8 + j] = fmaf(wgt, bf2f(b.us[j]), o[8 + j]);
        }
    }
    float avinv = 1.0f / wsum;
    short8 bf0, bf1;
    #pragma unroll
    for (int j = 0; j < 8; j++) {
        bf0[j] = (short)f2bf(o[j] * avinv);
        bf1[j] = (short)f2bf(o[8 + j] * avinv);
    }

    // ---- GEMM phase with 2-deep WoT register pipeline
    const ushort* apb = WoT + (size_t)(c0 + ql) * DIM_KH + g * 8;
    short8 a0c = *reinterpret_cast<const short8*>(apb);
    short8 a1c = *reinterpret_cast<const short8*>(apb + 32);
    #pragma unroll
    for (int ft = 0; ft < 16; ft++) {
        short8 a0n, a1n;
        if (ft < 15) {
            const ushort* apn = apb + (size_t)(ft + 1) * 16 * DIM_KH;
            a0n = *reinterpret_cast<const short8*>(apn);
            a1n = *reinterpret_cast<const short8*>(apn + 32);
        }
        floatx4 z = (floatx4){0.f, 0.f, 0.f, 0.f};
        z = __builtin_amdgcn_mfma_f32_16x16x32_bf16(a0c, bf0, z, 0, 0, 0);
        z = __builtin_amdgcn_mfma_f32_16x16x32_bf16(a1c, bf1, z, 0, 0, 0);
        int col = (c0 + 16 * ft + 4 * g) ^ ((ql & 7) << 2);
        uint2 p;
        p.x = (uint)f2bf(z[0]) | ((uint)f2bf(z[1]) << 16);
        p.y = (uint)f2bf(z[2]) | ((uint)f2bf(z[3]) << 16);
        *reinterpret_cast<uint2*>(&Ls[ql * 1024 + col]) = p;
        if (ft < 15) { a0c = a0n; a1c = a1n; }
    }
    __syncthreads();

    // ---- coalesced phase: thread owns row r, cols 4*(tid&15)+64j
    const int rsw = (r & 7) << 2;

    float4 yv[16];
    float s = 0.f, sq = 0.f;
    #pragma unroll
    for (int j = 0; j < 16; j++) {
        int col = cb + 64 * j;
        union { uint2 u; ushort us[4]; } a;
        a.u = *reinterpret_cast<const uint2*>(&Ls[r * 1024 + (col ^ rsw)]);
        float4 b4 = *reinterpret_cast<const float4*>(bo + col);
        float y0 = bf2f(a.us[0]) + xv[j].x + b4.x;
        float y1 = bf2f(a.us[1]) + xv[j].y + b4.y;
        float y2 = bf2f(a.us[2]) + xv[j].z + b4.z;
        float y3 = bf2f(a.us[3]) + xv[j].w + b4.w;
        yv[j] = (float4){y0, y1, y2, y3};
        s  += (y0 + y1) + (y2 + y3);
        sq += fmaf(y0, y0, fmaf(y1, y1, fmaf(y2, y2, y3 * y3)));
    }
    s  += __shfl_xor(s, 1);  s  += __shfl_xor(s, 2);
    s  += __shfl_xor(s, 4);  s  += __shfl_xor(s, 8);
    sq += __shfl_xor(sq, 1); sq += __shfl_xor(sq, 2);
    sq += __shfl_xor(sq, 4); sq += __shfl_xor(sq, 8);

    float mu  = s * (1.0f / 1024.0f);
    float var = fmaf(sq, (1.0f / 1024.0f), -mu * mu);
    float inv = rsqrtf(var + 1e-5f);

    float* Orow = Out + (size_t)(row0 + r) * DIM_D;
    #pragma unroll
    for (int j = 0; j < 16; j++) {
        int col = cb + 64 * j;
        float4 g4  = *reinterpret_cast<const float4*>(gamma + col);
        float4 be4 = *reinterpret_cast<const float4*>(beta + col);
        float4 ov;
        ov.x = fmaf((yv[j].x - mu) * inv, g4.x, be4.x);
        ov.y = fmaf((yv[j].y - mu) * inv, g4.y, be4.y);
        ov.z = fmaf((yv[j].z - mu) * inv, g4.z, be4.z);
        ov.w = fmaf((yv[j].w - mu) * inv, g4.w, be4.w);
        *reinterpret_cast<float4*>(Orow + col) = ov;
    }
}

// ---------------------------------------------------------------------------
extern "C" void kernel_launch(void* const* d_in, const int* in_sizes, int n_in,
                              void* d_out, int out_size, void* d_ws, size_t ws_size,
                              hipStream_t stream)
{
    (void)in_sizes; (void)n_in; (void)out_size; (void)ws_size;
    const float* X     = (const float*)d_in[0];
    const float* Wq    = (const float*)d_in[1];
    const float* bq    = (const float*)d_in[2];
    const float* Wk    = (const float*)d_in[3];
    const float* bk    = (const float*)d_in[4];
    const float* Wv    = (const float*)d_in[5];
    const float* bv    = (const float*)d_in[6];
    const float* Wo    = (const float*)d_in[7];
    const float* bo    = (const float*)d_in[8];
    const float* gamma = (const float*)d_in[9];
    const float* beta  = (const float*)d_in[10];
    float* Out = (float*)d_out;

    ushort* Qb  = (ushort*)d_ws;                          // 2 MB bf16
    ushort* Kb  = Qb + (size_t)NROWS * DIM_KH;            // 2 MB
    ushort* Vb  = Kb + (size_t)NROWS * DIM_KH;            // 2 MB
    ushort* WT  = Vb + (size_t)NROWS * DIM_KH;            // 384 KB
    ushort* WoT = WT + (size_t)192 * DIM_D;               // 128 KB
    ushort* OpartB = WoT + (size_t)DIM_D * DIM_KH;        // 8 MB bf16
    float*  Ml  = (float*)(OpartB + (size_t)KVSPLIT * NROWS * DIM_KH);  // 512 KB

    wconv_all<<<448, 256, 0, stream>>>(Wq, Wk, Wv, Wo, WT, WoT);
    qkv_mfma<<<dim3(256, 3), 256, 0, stream>>>(X, WT, bq, bk, bv, Qb, Kb, Vb);
    attn_mfma<<<dim3(SEQ/64, KVSPLIT, BATCH), 256, 0, stream>>>(Qb, Kb, Vb, OpartB, Ml);
    out_mfma<<<NROWS/16, 256, 0, stream>>>(X, OpartB, Ml, WoT, bo, gamma, beta, Out);
}

// Round 20
// 93.836 us; speedup vs baseline: 1.1523x; 1.0083x over previous
//
#include <hip/hip_runtime.h>
#include <hip/hip_bf16.h>

#define DIM_D 1024
#define DIM_KH 64
#define SEQ   2048
#define BATCH 8
#define NROWS (BATCH*SEQ)   // 16384
#define KVSPLIT 4
#define KEYS_PER_SPLIT (SEQ/KVSPLIT)   // 512

typedef __attribute__((ext_vector_type(8))) short short8;
typedef __attribute__((ext_vector_type(4))) short short4v;
typedef __attribute__((ext_vector_type(4))) float floatx4;

__device__ __forceinline__ ushort f2bf(float f) {
    union { __hip_bfloat16 h; ushort u; } cv;
    cv.h = __float2bfloat16(f);
    return cv.u;
}

__device__ __forceinline__ float bf2f(ushort u) {
    union { float f; uint u32; } c;
    c.u32 = (uint)u << 16;
    return c.f;
}

__device__ __forceinline__ uint4 pack8(float4 a, float4 b) {
    uint4 p;
    p.x = (uint)f2bf(a.x) | ((uint)f2bf(a.y) << 16);
    p.y = (uint)f2bf(a.z) | ((uint)f2bf(a.w) << 16);
    p.z = (uint)f2bf(b.x) | ((uint)f2bf(b.y) << 16);
    p.w = (uint)f2bf(b.z) | ((uint)f2bf(b.w) << 16);
    return p;
}

// ---------------------------------------------------------------------------
// Kernel 0: all weight converts in ONE launch.
// ---------------------------------------------------------------------------
__global__ void wconv_all(const float* __restrict__ Wq,
                          const float* __restrict__ Wk,
                          const float* __restrict__ Wv,
                          const float* __restrict__ Wo,
                          ushort* __restrict__ WT,
                          ushort* __restrict__ WoT)
{
    const int tid = threadIdx.x;
    if (blockIdx.x < 192) {
        const int n  = blockIdx.x;
        const int o  = n >> 6;
        const int nn = n & 63;
        const float* W = (o == 0) ? Wq : (o == 1) ? Wk : Wv;
        #pragma unroll
        for (int i = 0; i < 4; i++) {
            int k = tid + i * 256;
            WT[(size_t)n * DIM_D + k] = f2bf(W[(size_t)k * DIM_KH + nn]);
        }
    } else {
        const int blk = blockIdx.x - 192;
        const int n = blk * 4 + (tid >> 6);   // 0..1023
        const int k = tid & 63;
        WoT[(size_t)n * DIM_KH + k] = f2bf(Wo[(size_t)k * DIM_D + n]);
    }
}

// ---------------------------------------------------------------------------
// Kernel 1: QKV projection, bf16 MFMA, reg prefetch + double-buffered LDS.
// (unchanged — proven R8)
// ---------------------------------------------------------------------------
__global__ __launch_bounds__(256, 1) void qkv_mfma(
    const float* __restrict__ X, const ushort* __restrict__ WT,
    const float* __restrict__ bq, const float* __restrict__ bk,
    const float* __restrict__ bv,
    ushort* __restrict__ Qb, ushort* __restrict__ Kb, ushort* __restrict__ Vb)
{
    const int tid = threadIdx.x;
    const int m0  = blockIdx.x * 64;
    const int o   = blockIdx.y;          // 0=Q 1=K 2=V

    __shared__ ushort Xs[2][64 * 64];
    __shared__ ushort Wls[2][64 * 64];

    const int w  = tid >> 6;
    const int l  = tid & 63;
    const int ql = l & 15;
    const int g  = (l >> 4) & 3;
    const int swz = (ql & 7) << 3;

    const int sr  = tid >> 2;
    const int sc  = (tid & 3) << 4;
    const int ssw = (sr & 7) << 3;
    const float*  Xrow = X  + (size_t)(m0 + sr) * DIM_D + sc;
    const ushort* Wrow = WT + (size_t)(o * 64 + sr) * DIM_D + sc;

    float4 xr[4];
    uint4  wr[2];

    floatx4 acc[4];
    #pragma unroll
    for (int fn = 0; fn < 4; fn++) acc[fn] = (floatx4){0.f, 0.f, 0.f, 0.f};

    #pragma unroll
    for (int f = 0; f < 4; f++)
        xr[f] = *reinterpret_cast<const float4*>(Xrow + f * 4);
    #pragma unroll
    for (int h = 0; h < 2; h++)
        wr[h] = *reinterpret_cast<const uint4*>(Wrow + h * 8);
    #pragma unroll
    for (int h = 0; h < 2; h++) {
        *reinterpret_cast<uint4*>(&Xs[0][sr * 64 + ((sc + h * 8) ^ ssw)]) =
            pack8(xr[2 * h], xr[2 * h + 1]);
        *reinterpret_cast<uint4*>(&Wls[0][sr * 64 + ((sc + h * 8) ^ ssw)]) = wr[h];
    }
    __syncthreads();

    #pragma unroll
    for (int t = 0; t < 16; t++) {
        const int cur = t & 1;
        const int nxt = cur ^ 1;
        if (t < 15) {
            const int k1 = (t + 1) * 64;
            #pragma unroll
            for (int f = 0; f < 4; f++)
                xr[f] = *reinterpret_cast<const float4*>(Xrow + k1 + f * 4);
            #pragma unroll
            for (int h = 0; h < 2; h++)
                wr[h] = *reinterpret_cast<const uint4*>(Wrow + k1 + h * 8);
        }

        #pragma unroll
        for (int kk = 0; kk < 2; kk++) {
            short8 a = *reinterpret_cast<const short8*>(
                &Xs[cur][(16 * w + ql) * 64 + ((kk * 32 + g * 8) ^ swz)]);
            #pragma unroll
            for (int fn = 0; fn < 4; fn++) {
                short8 b = *reinterpret_cast<const short8*>(
                    &Wls[cur][(16 * fn + ql) * 64 + ((kk * 32 + g * 8) ^ swz)]);
                acc[fn] = __builtin_amdgcn_mfma_f32_16x16x32_bf16(a, b, acc[fn], 0, 0, 0);
            }
        }

        if (t < 15) {
            #pragma unroll
            for (int h = 0; h < 2; h++) {
                *reinterpret_cast<uint4*>(&Xs[nxt][sr * 64 + ((sc + h * 8) ^ ssw)]) =
                    pack8(xr[2 * h], xr[2 * h + 1]);
                *reinterpret_cast<uint4*>(&Wls[nxt][sr * 64 + ((sc + h * 8) ^ ssw)]) = wr[h];
            }
        }
        __syncthreads();
    }

    const float* bias = (o == 0) ? bq : (o == 1) ? bk : bv;
    ushort* O = (o == 0) ? Qb : (o == 1) ? Kb : Vb;
    float bvreg[4];
    #pragma unroll
    for (int fn = 0; fn < 4; fn++) bvreg[fn] = bias[16 * fn + ql];

    #pragma unroll
    for (int fn = 0; fn < 4; fn++) {
        #pragma unroll
        for (int r = 0; r < 4; r++) {
            int row = m0 + 16 * w + 4 * g + r;
            O[(size_t)row * DIM_KH + 16 * fn + ql] = f2bf(acc[fn][r] + bvreg[fn]);
        }
    }
}

// ---------------------------------------------------------------------------
// Kernel 2: flash attention, bf16 MFMA, split-KV, bf16 partials.
// NEW this round: R8's proven pattern applied — double-buffered Ks/VTs
// (32 KB), K/V prefetched into registers during compute, ONE barrier/tile.
// ---------------------------------------------------------------------------
__global__ __launch_bounds__(256) void attn_mfma(
    const ushort* __restrict__ Qb, const ushort* __restrict__ Kb,
    const ushort* __restrict__ Vb,
    ushort* __restrict__ OpartB, float* __restrict__ Ml)
{
    const int tid = threadIdx.x;
    const int w   = tid >> 6;
    const int l   = tid & 63;
    const int ql  = l & 15;
    const int g   = (l >> 4) & 3;
    const int q0  = blockIdx.x * 64;
    const int s   = blockIdx.y;          // KV split
    const int b   = blockIdx.z;
    const int swzq = (ql & 7) << 3;

    __shared__ ushort Ks[2][64 * 64];   // [buf][key][dim], swizzled (row&7)<<3
    __shared__ ushort VTs[2][64 * 64];  // [buf][dim][key], swizzled (dim&15)<<2

    // staging lane assignments
    const int krow0 = tid >> 3;          // K: rows tid>>3 and +32... (idx scheme below)
    const int kch   = tid & 7;
    const int kg    = tid >> 4, dg = tid & 15;
    const int key0  = kg * 4, dim0 = dg * 4;

    short8 qf[2];
    #pragma unroll
    for (int kk = 0; kk < 2; kk++) {
        qf[kk] = *reinterpret_cast<const short8*>(
            Qb + ((size_t)(b * SEQ + q0 + 16 * w + ql)) * DIM_KH + kk * 32 + g * 8);
    }

    floatx4 accv[4];
    #pragma unroll
    for (int fd = 0; fd < 4; fd++) accv[fd] = (floatx4){0.f, 0.f, 0.f, 0.f};
    float m_run = -3.0e38f, l_run = 0.f;

    const ushort* Kbb = Kb + (size_t)b * SEQ * DIM_KH;
    const ushort* Vbb = Vb + (size_t)b * SEQ * DIM_KH;
    const int t_begin = s * KEYS_PER_SPLIT;
    const int NT = KEYS_PER_SPLIT / 64;   // 8 tiles

    uint4 kr[2];
    uint2 vr[4];

    // prologue: load tile 0 into regs, write buf 0
    #pragma unroll
    for (int i = 0; i < 2; i++) {
        int row = (tid + i * 256) >> 3;
        kr[i] = *reinterpret_cast<const uint4*>(
            Kbb + (size_t)(t_begin + row) * DIM_KH + kch * 8);
    }
    #pragma unroll
    for (int i = 0; i < 4; i++)
        vr[i] = *reinterpret_cast<const uint2*>(
            Vbb + (size_t)(t_begin + key0 + i) * DIM_KH + dim0);
    #pragma unroll
    for (int i = 0; i < 2; i++) {
        int row = (tid + i * 256) >> 3;
        *reinterpret_cast<uint4*>(
            &Ks[0][row * 64 + ((kch * 8) ^ ((row & 7) << 3))]) = kr[i];
    }
    #pragma unroll
    for (int j = 0; j < 4; j++) {
        uint e0 = (j == 0) ? (vr[0].x & 0xffffu) : (j == 1) ? (vr[0].x >> 16)
                : (j == 2) ? (vr[0].y & 0xffffu) : (vr[0].y >> 16);
        uint e1 = (j == 0) ? (vr[1].x & 0xffffu) : (j == 1) ? (vr[1].x >> 16)
                : (j == 2) ? (vr[1].y & 0xffffu) : (vr[1].y >> 16);
        uint e2 = (j == 0) ? (vr[2].x & 0xffffu) : (j == 1) ? (vr[2].x >> 16)
                : (j == 2) ? (vr[2].y & 0xffffu) : (vr[2].y >> 16);
        uint e3 = (j == 0) ? (vr[3].x & 0xffffu) : (j == 1) ? (vr[3].x >> 16)
                : (j == 2) ? (vr[3].y & 0xffffu) : (vr[3].y >> 16);
        uint2 p; p.x = e0 | (e1 << 16); p.y = e2 | (e3 << 16);
        int dim = dim0 + j;
        *reinterpret_cast<uint2*>(
            &VTs[0][dim * 64 + (key0 ^ ((dim & 15) << 2))]) = p;
    }
    __syncthreads();

    for (int ti = 0; ti < NT; ti++) {
        const int cur = ti & 1;
        const int nxt = cur ^ 1;

        // prefetch next tile into registers (in flight during compute)
        if (ti < NT - 1) {
            const int t1 = t_begin + (ti + 1) * 64;
            #pragma unroll
            for (int i = 0; i < 2; i++) {
                int row = (tid + i * 256) >> 3;
                kr[i] = *reinterpret_cast<const uint4*>(
                    Kbb + (size_t)(t1 + row) * DIM_KH + kch * 8);
            }
            #pragma unroll
            for (int i = 0; i < 4; i++)
                vr[i] = *reinterpret_cast<const uint2*>(
                    Vbb + (size_t)(t1 + key0 + i) * DIM_KH + dim0);
        }

        // ---- compute tile ti from buffer cur ----
        floatx4 sfrag[4];
        #pragma unroll
        for (int f = 0; f < 4; f++) {
            sfrag[f] = (floatx4){0.f, 0.f, 0.f, 0.f};
            #pragma unroll
            for (int kk = 0; kk < 2; kk++) {
                short8 a = *reinterpret_cast<const short8*>(
                    &Ks[cur][(16 * f + ql) * 64 + ((kk * 32 + g * 8) ^ swzq)]);
                sfrag[f] = __builtin_amdgcn_mfma_f32_16x16x32_bf16(a, qf[kk], sfrag[f], 0, 0, 0);
            }
        }

        float mt = -3.0e38f;
        #pragma unroll
        for (int f = 0; f < 4; f++)
            #pragma unroll
            for (int r = 0; r < 4; r++) mt = fmaxf(mt, sfrag[f][r]);
        mt = fmaxf(mt, __shfl_xor(mt, 16));
        mt = fmaxf(mt, __shfl_xor(mt, 32));
        float m_new = fmaxf(m_run, mt);
        float sc = __expf((m_run - m_new) * 0.125f);
        float psum = 0.f;
        ushort pb[4][4];
        #pragma unroll
        for (int f = 0; f < 4; f++)
            #pragma unroll
            for (int r = 0; r < 4; r++) {
                float p = __expf((sfrag[f][r] - m_new) * 0.125f);
                pb[f][r] = f2bf(p);
                psum += p;
            }
        psum += __shfl_xor(psum, 16);
        psum += __shfl_xor(psum, 32);
        l_run = l_run * sc + psum;
        m_run = m_new;

        float s0 = __shfl(sc, 4 * g + 0);
        float s1 = __shfl(sc, 4 * g + 1);
        float s2 = __shfl(sc, 4 * g + 2);
        float s3 = __shfl(sc, 4 * g + 3);
        #pragma unroll
        for (int fd = 0; fd < 4; fd++) {
            accv[fd][0] *= s0; accv[fd][1] *= s1;
            accv[fd][2] *= s2; accv[fd][3] *= s3;
        }

        short8 pa_lo, pa_hi;
        pa_lo[0] = (short)pb[0][0]; pa_lo[1] = (short)pb[0][1];
        pa_lo[2] = (short)pb[0][2]; pa_lo[3] = (short)pb[0][3];
        pa_lo[4] = (short)pb[1][0]; pa_lo[5] = (short)pb[1][1];
        pa_lo[6] = (short)pb[1][2]; pa_lo[7] = (short)pb[1][3];
        pa_hi[0] = (short)pb[2][0]; pa_hi[1] = (short)pb[2][1];
        pa_hi[2] = (short)pb[2][2]; pa_hi[3] = (short)pb[2][3];
        pa_hi[4] = (short)pb[3][0]; pa_hi[5] = (short)pb[3][1];
        pa_hi[6] = (short)pb[3][2]; pa_hi[7] = (short)pb[3][3];

        #pragma unroll
        for (int fd = 0; fd < 4; fd++) {
            int dim = 16 * fd + ql;
            int base = dim * 64;
            int sw = (dim & 15) << 2;
            short4v v0 = *reinterpret_cast<const short4v*>(&VTs[cur][base + ((4 * g) ^ sw)]);
            short4v v1 = *reinterpret_cast<const short4v*>(&VTs[cur][base + ((16 + 4 * g) ^ sw)]);
            short8 bb;
            bb[0] = v0[0]; bb[1] = v0[1]; bb[2] = v0[2]; bb[3] = v0[3];
            bb[4] = v1[0]; bb[5] = v1[1]; bb[6] = v1[2]; bb[7] = v1[3];
            accv[fd] = __builtin_amdgcn_mfma_f32_16x16x32_bf16(pa_lo, bb, accv[fd], 0, 0, 0);
            short4v v2 = *reinterpret_cast<const short4v*>(&VTs[cur][base + ((32 + 4 * g) ^ sw)]);
            short4v v3 = *reinterpret_cast<const short4v*>(&VTs[cur][base + ((48 + 4 * g) ^ sw)]);
            short8 bb2;
            bb2[0] = v2[0]; bb2[1] = v2[1]; bb2[2] = v2[2]; bb2[3] = v2[3];
            bb2[4] = v3[0]; bb2[5] = v3[1]; bb2[6] = v3[2]; bb2[7] = v3[3];
            accv[fd] = __builtin_amdgcn_mfma_f32_16x16x32_bf16(pa_hi, bb2, accv[fd], 0, 0, 0);
        }

        // ---- write prefetched tile into the other buffer; one barrier ----
        if (ti < NT - 1) {
            #pragma unroll
            for (int i = 0; i < 2; i++) {
                int row = (tid + i * 256) >> 3;
                *reinterpret_cast<uint4*>(
                    &Ks[nxt][row * 64 + ((kch * 8) ^ ((row & 7) << 3))]) = kr[i];
            }
            #pragma unroll
            for (int j = 0; j < 4; j++) {
                uint e0 = (j == 0) ? (vr[0].x & 0xffffu) : (j == 1) ? (vr[0].x >> 16)
                        : (j == 2) ? (vr[0].y & 0xffffu) : (vr[0].y >> 16);
                uint e1 = (j == 0) ? (vr[1].x & 0xffffu) : (j == 1) ? (vr[1].x >> 16)
                        : (j == 2) ? (vr[1].y & 0xffffu) : (vr[1].y >> 16);
                uint e2 = (j == 0) ? (vr[2].x & 0xffffu) : (j == 1) ? (vr[2].x >> 16)
                        : (j == 2) ? (vr[2].y & 0xffffu) : (vr[2].y >> 16);
                uint e3 = (j == 0) ? (vr[3].x & 0xffffu) : (j == 1) ? (vr[3].x >> 16)
                        : (j == 2) ? (vr[3].y & 0xffffu) : (vr[3].y >> 16);
                uint2 p; p.x = e0 | (e1 << 16); p.y = e2 | (e3 << 16);
                int dim = dim0 + j;
                *reinterpret_cast<uint2*>(
                    &VTs[nxt][dim * 64 + (key0 ^ ((dim & 15) << 2))]) = p;
            }
        }
        __syncthreads();
    }

    const size_t rid0 = (size_t)b * SEQ + q0;
    if (g == 0) {
        size_t rid = rid0 + 16 * w + ql;
        Ml[((size_t)s * NROWS + rid) * 2 + 0] = m_run;
        Ml[((size_t)s * NROWS + rid) * 2 + 1] = l_run;
    }
    #pragma unroll
    for (int fd = 0; fd < 4; fd++) {
        int col = 16 * fd + ql;
        size_t rbase = (size_t)s * NROWS + rid0 + 16 * w + 4 * g;
        OpartB[(rbase + 0) * DIM_KH + col] = f2bf(accv[fd][0]);
        OpartB[(rbase + 1) * DIM_KH + col] = f2bf(accv[fd][1]);
        OpartB[(rbase + 2) * DIM_KH + col] = f2bf(accv[fd][2]);
        OpartB[(rbase + 3) * DIM_KH + col] = f2bf(accv[fd][3]);
    }
}

// ---------------------------------------------------------------------------
// Kernel 3: fused combine + out-proj + residual + LayerNorm. (R12 exact —
// best measured variant.)
// ---------------------------------------------------------------------------
__global__ __launch_bounds__(256, 1) void out_mfma(
    const float* __restrict__ X, const ushort* __restrict__ OpartB,
    const float* __restrict__ Ml,
    const ushort* __restrict__ WoT, const float* __restrict__ bo,
    const float* __restrict__ gamma, const float* __restrict__ beta,
    float* __restrict__ Out)
{
    const int tid = threadIdx.x;
    const int w   = tid >> 6;
    const int l   = tid & 63;
    const int ql  = l & 15;
    const int g   = (l >> 4) & 3;
    const int row0 = blockIdx.x * 16;
    const int c0  = w * 256;

    __shared__ ushort Ls[16 * 1024];   // 32 KB bf16

    const int r  = tid >> 4;
    const int cb = (tid & 15) * 4;
    const float* Xrow = X + (size_t)(row0 + r) * DIM_D;
    float4 xv[16];
    #pragma unroll
    for (int j = 0; j < 16; j++)
        xv[j] = *reinterpret_cast<const float4*>(Xrow + cb + 64 * j);

    const size_t rid = (size_t)row0 + ql;
    float m[KVSPLIT], lv[KVSPLIT];
    float M = -3.0e38f;
    #pragma unroll
    for (int s = 0; s < KVSPLIT; s++) {
        float2 t = *reinterpret_cast<const float2*>(Ml + ((size_t)s * NROWS + rid) * 2);
        m[s] = t.x; lv[s] = t.y;
        M = fmaxf(M, m[s]);
    }
    float wsum = 0.f;
    float o[16];
    #pragma unroll
    for (int d = 0; d < 16; d++) o[d] = 0.f;
    #pragma unroll
    for (int s = 0; s < KVSPLIT; s++) {
        float wgt = __expf((m[s] - M) * 0.125f);
        wsum = fmaf(wgt, lv[s], wsum);
        const ushort* op = OpartB + ((size_t)s * NROWS + rid) * DIM_KH;
        union { uint4 u; ushort us[8]; } a, b;
        a.u = *reinterpret_cast<const uint4*>(op + g * 8);
        b.u = *reinterpret_cast<const uint4*>(op + 32 + g * 8);
        #pragma unroll
        for (int j = 0; j < 8; j++) {
            o[j]     = fmaf(wgt, bf2f(a.us[j]), o[j]);
            o[8 + j] = fmaf(wgt, bf2f(b.us[j]), o[8 + j]);
        }
    }
    float avinv = 1.0f / wsum;
    short8 bf0, bf1;
    #pragma unroll
    for (int j = 0; j < 8; j++) {
        bf0[j] = (short)f2bf(o[j] * avinv);
        bf1[j] = (short)f2bf(o[8 + j] * avinv);
    }

    const ushort* apb = WoT + (size_t)(c0 + ql) * DIM_KH + g * 8;
    short8 a0c = *reinterpret_cast<const short8*>(apb);
    short8 a1c = *reinterpret_cast<const short8*>(apb + 32);
    #pragma unroll
    for (int ft = 0; ft < 16; ft++) {
        short8 a0n, a1n;
        if (ft < 15) {
            const ushort* apn = apb + (size_t)(ft + 1) * 16 * DIM_KH;
            a0n = *reinterpret_cast<const short8*>(apn);
            a1n = *reinterpret_cast<const short8*>(apn + 32);
        }
        floatx4 z = (floatx4){0.f, 0.f, 0.f, 0.f};
        z = __builtin_amdgcn_mfma_f32_16x16x32_bf16(a0c, bf0, z, 0, 0, 0);
        z = __builtin_amdgcn_mfma_f32_16x16x32_bf16(a1c, bf1, z, 0, 0, 0);
        int col = (c0 + 16 * ft + 4 * g) ^ ((ql & 7) << 2);
        uint2 p;
        p.x = (uint)f2bf(z[0]) | ((uint)f2bf(z[1]) << 16);
        p.y = (uint)f2bf(z[2]) | ((uint)f2bf(z[3]) << 16);
        *reinterpret_cast<uint2*>(&Ls[ql * 1024 + col]) = p;
        if (ft < 15) { a0c = a0n; a1c = a1n; }
    }
    __syncthreads();

    const int rsw = (r & 7) << 2;

    float4 yv[16];
    float s = 0.f, sq = 0.f;
    #pragma unroll
    for (int j = 0; j < 16; j++) {
        int col = cb + 64 * j;
        union { uint2 u; ushort us[4]; } a;
        a.u = *reinterpret_cast<const uint2*>(&Ls[r * 1024 + (col ^ rsw)]);
        float4 b4 = *reinterpret_cast<const float4*>(bo + col);
        float y0 = bf2f(a.us[0]) + xv[j].x + b4.x;
        float y1 = bf2f(a.us[1]) + xv[j].y + b4.y;
        float y2 = bf2f(a.us[2]) + xv[j].z + b4.z;
        float y3 = bf2f(a.us[3]) + xv[j].w + b4.w;
        yv[j] = (float4){y0, y1, y2, y3};
        s  += (y0 + y1) + (y2 + y3);
        sq += fmaf(y0, y0, fmaf(y1, y1, fmaf(y2, y2, y3 * y3)));
    }
    s  += __shfl_xor(s, 1);  s  += __shfl_xor(s, 2);
    s  += __shfl_xor(s, 4);  s  += __shfl_xor(s, 8);
    sq += __shfl_xor(sq, 1); sq += __shfl_xor(sq, 2);
    sq += __shfl_xor(sq, 4); sq += __shfl_xor(sq, 8);

    float mu  = s * (1.0f / 1024.0f);
    float var = fmaf(sq, (1.0f / 1024.0f), -mu * mu);
    float inv = rsqrtf(var + 1e-5f);

    float* Orow = Out + (size_t)(row0 + r) * DIM_D;
    #pragma unroll
    for (int j = 0; j < 16; j++) {
        int col = cb + 64 * j;
        float4 g4  = *reinterpret_cast<const float4*>(gamma + col);
        float4 be4 = *reinterpret_cast<const float4*>(beta + col);
        float4 ov;
        ov.x = fmaf((yv[j].x - mu) * inv, g4.x, be4.x);
        ov.y = fmaf((yv[j].y - mu) * inv, g4.y, be4.y);
        ov.z = fmaf((yv[j].z - mu) * inv, g4.z, be4.z);
        ov.w = fmaf((yv[j].w - mu) * inv, g4.w, be4.w);
        *reinterpret_cast<float4*>(Orow + col) = ov;
    }
}

// ---------------------------------------------------------------------------
extern "C" void kernel_launch(void* const* d_in, const int* in_sizes, int n_in,
                              void* d_out, int out_size, void* d_ws, size_t ws_size,
                              hipStream_t stream)
{
    (void)in_sizes; (void)n_in; (void)out_size; (void)ws_size;
    const float* X     = (const float*)d_in[0];
    const float* Wq    = (const float*)d_in[1];
    const float* bq    = (const float*)d_in[2];
    const float* Wk    = (const float*)d_in[3];
    const float* bk    = (const float*)d_in[4];
    const float* Wv    = (const float*)d_in[5];
    const float* bv    = (const float*)d_in[6];
    const float* Wo    = (const float*)d_in[7];
    const float* bo    = (const float*)d_in[8];
    const float* gamma = (const float*)d_in[9];
    const float* beta  = (const float*)d_in[10];
    float* Out = (float*)d_out;

    ushort* Qb  = (ushort*)d_ws;                          // 2 MB bf16
    ushort* Kb  = Qb + (size_t)NROWS * DIM_KH;            // 2 MB
    ushort* Vb  = Kb + (size_t)NROWS * DIM_KH;            // 2 MB
    ushort* WT  = Vb + (size_t)NROWS * DIM_KH;            // 384 KB
    ushort* WoT = WT + (size_t)192 * DIM_D;               // 128 KB
    ushort* OpartB = WoT + (size_t)DIM_D * DIM_KH;        // 8 MB bf16
    float*  Ml  = (float*)(OpartB + (size_t)KVSPLIT * NROWS * DIM_KH);  // 512 KB

    wconv_all<<<448, 256, 0, stream>>>(Wq, Wk, Wv, Wo, WT, WoT);
    qkv_mfma<<<dim3(256, 3), 256, 0, stream>>>(X, WT, bq, bk, bv, Qb, Kb, Vb);
    attn_mfma<<<dim3(SEQ/64, KVSPLIT, BATCH), 256, 0, stream>>>(Qb, Kb, Vb, OpartB, Ml);
    out_mfma<<<NROWS/16, 256, 0, stream>>>(X, OpartB, Ml, WoT, bo, gamma, beta, Out);
}